// Round 8
// baseline (1579.533 us; speedup 1.0000x reference)
//
#include <hip/hip_runtime.h>

#define B 8
#define NOBJ 128
#define NATTR 4
#define T 12
#define MC 2048
#define E 128
#define IDD 64
#define AD 64
#define HD 256
#define C 2176

typedef short s16x8 __attribute__((ext_vector_type(8)));
typedef float f32x4 __attribute__((ext_vector_type(4)));

__device__ inline unsigned short f2b(float f) {
  union { float f; unsigned u; } v; v.f = f;
  unsigned r = v.u + 0x7FFFu + ((v.u >> 16) & 1u);
  return (unsigned short)(r >> 16);
}
__device__ inline float b2f(unsigned short u) {
  union { unsigned u; float f; } v; v.u = ((unsigned)u) << 16;
  return v.f;
}

// coherent (MALL-routed) accessors: bypass non-coherent per-XCD L1/L2, no fences
__device__ __forceinline__ void st_coh_u64(unsigned long long* p, unsigned long long v) {
  __hip_atomic_store(p, v, __ATOMIC_RELAXED, __HIP_MEMORY_SCOPE_AGENT);
}
__device__ __forceinline__ unsigned long long ld_coh_u64(const unsigned long long* p) {
  return __hip_atomic_load(p, __ATOMIC_RELAXED, __HIP_MEMORY_SCOPE_AGENT);
}
__device__ __forceinline__ void st_coh_u32(unsigned* p, unsigned v) {
  __hip_atomic_store(p, v, __ATOMIC_RELAXED, __HIP_MEMORY_SCOPE_AGENT);
}
__device__ __forceinline__ unsigned ld_coh_u32(const unsigned* p) {
  return __hip_atomic_load(p, __ATOMIC_RELAXED, __HIP_MEMORY_SCOPE_AGENT);
}
__device__ __forceinline__ void st_coh_f32(float* p, float v) {
  union { float f; unsigned u; } c; c.f = v;
  __hip_atomic_store((unsigned*)p, c.u, __ATOMIC_RELAXED, __HIP_MEMORY_SCOPE_AGENT);
}
__device__ __forceinline__ float ld_coh_f32(const float* p) {
  union { unsigned u; float f; } c;
  c.u = __hip_atomic_load((const unsigned*)p, __ATOMIC_RELAXED, __HIP_MEMORY_SCOPE_AGENT);
  return c.f;
}
__device__ __forceinline__ s16x8 ld_coh_b16x8(const unsigned short* p) {
  union { unsigned long long u[2]; s16x8 v; } r;
  r.u[0] = ld_coh_u64((const unsigned long long*)p);
  r.u[1] = ld_coh_u64((const unsigned long long*)p + 1);
  return r.v;
}

// LDS swizzles: XOR row bits into the 16B-slot index (conflict-free b128 reads)
__device__ __forceinline__ int gidx(int r, int c) {   // g [64][128]
  return r * 128 + ((((c >> 3) ^ (r & 15)) << 3) | (c & 7));
}
__device__ __forceinline__ int hidx(int r, int c) {   // h [64][256]
  return r * 256 + ((((c >> 3) ^ (r & 15)) << 3) | (c & 7));
}
__device__ __forceinline__ int mtidx(int r, int c) {  // mt [128][128]
  return r * 128 + ((((c >> 3) ^ (r & 15)) << 3) | (c & 7));
}

// ---------------- setup kernel 1: build + weight cvt + flag zero ----------------
__global__ __launch_bounds__(256) void k_setup1(
    const int* __restrict__ scene,
    const float* __restrict__ aein, const float* __restrict__ aeout,
    const float* __restrict__ aeid,
    const float* __restrict__ cein, const float* __restrict__ ceout,
    const float* __restrict__ ceid,
    const float* __restrict__ aw1, const float* __restrict__ aw2,
    const float* __restrict__ mw1, const float* __restrict__ mw2,
    unsigned short* __restrict__ dendron_bf, float* __restrict__ axon,
    float* __restrict__ identity,
    unsigned short* __restrict__ w1_bf, unsigned short* __restrict__ w2_bf,
    float* __restrict__ mw1T, float* __restrict__ mw2T,
    unsigned* __restrict__ flags) {
  int blk = blockIdx.x;
  int tid = threadIdx.x;
  if (blk < 4352) {
    int gid = blk * 2 + (tid >> 7);
    int e = tid & 127;
    int b = gid / C, j = gid % C;
    float din, dout, did = 0.f;
    if (j < MC) {
      din  = cein[j * E + e];
      dout = ceout[j * E + e];
      if (e < IDD) did = ceid[j * IDD + e];
    } else {
      int obj = j - MC;
      float sIn = 0.f, sOut = 0.f, sId = 0.f;
      for (int a = 0; a < NATTR; a++) {
        int s = scene[(b * NOBJ + obj) * NATTR + a];
        float m = (s != -1) ? 1.f : 0.f;
        int idx = s + 1;
        sIn  += aein[idx * E + e] * m;
        sOut += aeout[idx * E + e] * m;
        if (e < IDD) sId += aeid[idx * IDD + e] * m;
      }
      din = sIn; dout = sOut; did = sId;
    }
    dendron_bf[(size_t)gid * E + e] = f2b(din);
    axon[(size_t)gid * E + e] = dout;
    if (e < IDD) identity[(size_t)gid * IDD + e] = did;
  } else if (blk < 4544) {
    int i = (blk - 4352) * 256 + tid;
    if (i < HD * E)  w1_bf[i] = f2b(aw1[i]);
    if (i < AD * HD) w2_bf[i] = f2b(aw2[i]);
    if (i < 192 * HD) { int c = i / HD, k = i % HD; mw1T[c * HD + k] = mw1[k * 192 + c]; }
    if (i < HD * AD)  { int k = i / AD, a = i % AD; mw2T[k * AD + a] = mw2[a * HD + k]; }
  } else {
    for (int i = tid; i < 576; i += 256) flags[i] = 0u;
  }
}

// ---------------- setup kernel 2: transA/init + meta + proj ----------------
__global__ __launch_bounds__(256) void k_setup2(
    const float* __restrict__ axon, const float* __restrict__ identity,
    const float* __restrict__ att_init,
    const int* __restrict__ prog_op, const int* __restrict__ prog_arg,
    const float* __restrict__ ceout,
    const float* __restrict__ mw1T, const float* __restrict__ mb1,
    const float* __restrict__ mw2T, const float* __restrict__ mb2,
    unsigned short* __restrict__ axonT, unsigned short* __restrict__ idT_g,
    unsigned short* __restrict__ siaT,
    float* __restrict__ meta_all, float* __restrict__ proj_all) {
  int blk = blockIdx.x;
  int tid = threadIdx.x;
  if (blk < 272) {
    int b = blk / 34, jc = blk % 34;
    int j0 = jc * 64;
    __shared__ float ax[64][129];
    __shared__ float idb[64][65];
    int lane = tid & 63;
    float s = att_init[lane];
    s += __shfl_xor(s, 1, 64);  s += __shfl_xor(s, 2, 64);
    s += __shfl_xor(s, 4, 64);  s += __shfl_xor(s, 8, 64);
    s += __shfl_xor(s, 16, 64); s += __shfl_xor(s, 32, 64);
    float am0 = s * (1.f / AD);
    for (int i = tid; i < 64 * 128; i += 256) {
      int j = i >> 7, e = i & 127;
      ax[j][e] = axon[(size_t)(b * C + j0 + j) * E + e];
    }
    for (int i = tid; i < 64 * 64; i += 256) {
      int j = i >> 6, d = i & 63;
      idb[j][d] = identity[(size_t)(b * C + j0 + j) * IDD + d];
    }
    __syncthreads();
    for (int i = tid; i < 128 * 64; i += 256) {
      int e = i >> 6, jj = i & 63;
      axonT[(size_t)(b * E + e) * C + j0 + jj] = f2b(ax[jj][e]);
    }
    for (int i = tid; i < 64 * 64; i += 256) {
      int d = i >> 6, jj = i & 63;
      idT_g[(size_t)(b * 64 + d) * C + j0 + jj] = f2b(idb[jj][d]);
      siaT[(size_t)(b * 128 + d) * C + j0 + jj] = f2b(idb[jj][d] * am0);
      siaT[(size_t)(b * 128 + 64 + d) * C + j0 + jj] = f2b(att_init[d] * am0);
    }
  } else if (blk < 280) {
    int b = blk - 272;
    __shared__ float x[192];
    __shared__ float h[HD];
    __shared__ float meta[AD];
    if (tid < AD) meta[tid] = att_init[tid];
    __syncthreads();
    for (int t = 0; t < T; t++) {
      int arg = prog_arg[b * T + t];
      if (tid < AD) x[tid] = meta[tid];
      else if (tid < 192) x[tid] = ceout[arg * E + (tid - 64)];
      __syncthreads();
      float s = mb1[tid];
      for (int c = 0; c < 192; c++) s += x[c] * mw1T[c * HD + tid];
      h[tid] = fmaxf(s, 0.f);
      __syncthreads();
      if (tid < AD) {
        float o = mb2[tid];
        for (int k = 0; k < HD; k++) o += h[k] * mw2T[k * AD + tid];
        float m = (prog_op[b * T + t] == 0) ? 1.f : 0.f;
        float nm = m * o + (1.f - m) * meta[tid];
        meta[tid] = nm;
        meta_all[(t * B + b) * AD + tid] = nm;
      }
      __syncthreads();
    }
  } else {
    int gid = (blk - 280) * 4 + (tid >> 6);
    int lane = tid & 63;
    int b = gid / C, i = gid % C;
    float a0 = axon[(size_t)gid * E + lane];
    float a1 = axon[(size_t)gid * E + 64 + lane];
    for (int t = 0; t < T; t++) {
      int arg = prog_arg[b * T + t];
      float p = a0 * ceout[arg * E + lane] + a1 * ceout[arg * E + 64 + lane];
      for (int off = 1; off < 64; off <<= 1) p += __shfl_xor(p, off, 64);
      if (lane == 0) proj_all[(size_t)(t * B + b) * C + i] = p * (1.f / E);
    }
  }
}

// ---------------- the persistent 12-step kernel ----------------
// 272 blocks (34/batch). ch<4 produce 32x128 M-tiles. All co-resident (2+ blocks/CU).
__global__ __launch_bounds__(256, 2) void k_steps(
    const unsigned short* __restrict__ dendron_bf,
    const unsigned short* __restrict__ axonT,
    const unsigned short* __restrict__ idT_g,
    unsigned short* __restrict__ siaT,
    const unsigned short* __restrict__ w1_bf, const float* __restrict__ b1g,
    const unsigned short* __restrict__ w2_bf, const float* __restrict__ b2g,
    const float* __restrict__ proj_all, const float* __restrict__ meta_all,
    const int* __restrict__ prog_op, const float* __restrict__ att_init,
    unsigned long long* __restrict__ Mt64,
    float* __restrict__ rowmean, float* __restrict__ out,
    float* __restrict__ att_hist, float* __restrict__ ins_hist,
    float* __restrict__ trans_hist,
    unsigned* __restrict__ mflag, unsigned* __restrict__ cflag,
    unsigned* __restrict__ sflag) {
  const int blk = blockIdx.x;
  const int b = blk / 34, ch = blk % 34, j0 = ch * 64;
  const int tid = threadIdx.x;
  const int w = tid >> 6, lane = tid & 63, lr = lane & 15, lg = lane >> 4;

  __shared__ unsigned short smem[24576];           // 48 KB overlay
  __shared__ float am_l[64];
  __shared__ float red[256];
  unsigned short* g_l = smem;                      // bytes [0,16K)
  unsigned short* mt  = smem + 8192;               // bytes [16K,48K)
  unsigned short* h_l = smem + 8192;

  const f32x4 z = {0.f, 0.f, 0.f, 0.f};

  // attention state in registers for all 12 steps
  float att[4][4];
  #pragma unroll
  for (int n = 0; n < 4; n++) {
    float v0 = att_init[n * 16 + lr];
    #pragma unroll
    for (int v = 0; v < 4; v++) att[n][v] = v0;
  }
  // step-invariant dendron A-fragments for phase A
  s16x8 afr[4];
  #pragma unroll
  for (int ke = 0; ke < 4; ke++)
    afr[ke] = *(const s16x8*)(dendron_bf + (size_t)(b * C + j0 + w * 16 + lr) * E + ke * 32 + lg * 8);

  float amr[4];

  for (int t = 0; t < T; t++) {
    const unsigned ph = (unsigned)(t + 1);
    // ---- producers: 4 per batch, each a unique 32x128 M-tile ----
    if (ch < 4) {
      if (t > 0) {
        if (tid < 34) {
          while (ld_coh_u32(cflag + b * 34 + tid) < (unsigned)t) __builtin_amdgcn_s_sleep(2);
        }
      }
      __syncthreads();
      const int d0 = ch * 32;
      const int eh = w & 1, kh = w >> 1;
      const int kbase = kh * 1088;
      const unsigned short* ap0 = siaT + (size_t)(b * 128 + d0 + lr) * C + kbase + lg * 8;
      const unsigned short* ap1 = ap0 + (size_t)16 * C;
      const unsigned short* bp  = axonT + (size_t)(b * E + eh * 64 + lr) * C + kbase + lg * 8;
      f32x4 pa[2][4];
      #pragma unroll
      for (int dp = 0; dp < 2; dp++)
        #pragma unroll
        for (int n = 0; n < 4; n++) pa[dp][n] = z;
      for (int kk = 0; kk < 34; kk++) {
        int k0 = kk * 32;
        s16x8 A0 = ld_coh_b16x8(ap0 + k0);
        s16x8 A1 = ld_coh_b16x8(ap1 + k0);
        #pragma unroll
        for (int n = 0; n < 4; n++) {
          s16x8 Bn = *(const s16x8*)(bp + (size_t)n * 16 * C + k0);
          pa[0][n] = __builtin_amdgcn_mfma_f32_16x16x32_bf16(A0, Bn, pa[0][n], 0, 0, 0);
          pa[1][n] = __builtin_amdgcn_mfma_f32_16x16x32_bf16(A1, Bn, pa[1][n], 0, 0, 0);
        }
      }
      float* pls = (float*)smem;                   // [2][32][132] f32
      #pragma unroll
      for (int dp = 0; dp < 2; dp++)
        #pragma unroll
        for (int n = 0; n < 4; n++)
          #pragma unroll
          for (int v = 0; v < 4; v++)
            pls[(kh * 32 + dp * 16 + lg * 4 + v) * 132 + eh * 64 + n * 16 + lr] = pa[dp][n][v];
      __syncthreads();
      {
        int r = tid >> 3, cb = (tid & 7) * 16;
        const float* p0 = pls + r * 132 + cb;
        const float* p1 = pls + (32 + r) * 132 + cb;
        #pragma unroll
        for (int q = 0; q < 4; q++) {
          unsigned long long pk = 0;
          #pragma unroll
          for (int x = 0; x < 4; x++) {
            float sv = p0[q * 4 + x] + p1[q * 4 + x];
            pk |= (unsigned long long)f2b(sv) << (16 * x);
          }
          st_coh_u64(Mt64 + ((size_t)(b * 128 + d0 + r) * 128 + cb + q * 4) / 4, pk);
        }
      }
      asm volatile("s_waitcnt vmcnt(0)" ::: "memory");
      __syncthreads();
      if (tid == 0) st_coh_u32(mflag + b * 4 + ch, ph);
    }
    // ---- all blocks: wait for this batch's 4 M-tiles ----
    if (tid < 4) {
      while (ld_coh_u32(mflag + b * 4 + tid) < ph) __builtin_amdgcn_s_sleep(2);
    }
    __syncthreads();
    // ---- stage Mt -> LDS (swizzled, coherent loads) ----
    {
      const unsigned long long* mtp = Mt64 + (size_t)b * 4096;
      #pragma unroll
      for (int k = 0; k < 16; k++) {
        int idx = tid + k * 256;
        unsigned long long v = ld_coh_u64(mtp + idx);
        int r = idx >> 5, c4 = (idx & 31) * 4;
        *(unsigned long long*)&mt[mtidx(r, c4)] = v;
      }
    }
    __syncthreads();
    // ---- phase A: g = dendron @ M / C ----
    {
      #pragma unroll
      for (int n = 0; n < 8; n++) {
        f32x4 acc = z;
        #pragma unroll
        for (int ke = 0; ke < 4; ke++) {
          s16x8 bf = *(const s16x8*)&mt[mtidx(n * 16 + lr, ke * 32 + lg * 8)];
          acc = __builtin_amdgcn_mfma_f32_16x16x32_bf16(afr[ke], bf, acc, 0, 0, 0);
        }
        #pragma unroll
        for (int v = 0; v < 4; v++)
          g_l[gidx(w * 16 + lg * 4 + v, n * 16 + lr)] = f2b(acc[v] * (1.f / C));
      }
    }
    __syncthreads();
    // ---- phase B: h = relu(g @ w1^T + b1) ----
    {
      s16x8 gf[4];
      #pragma unroll
      for (int kd = 0; kd < 4; kd++)
        gf[kd] = *(const s16x8*)&g_l[gidx(w * 16 + lr, kd * 32 + lg * 8)];
      #pragma unroll
      for (int n = 0; n < 16; n++) {
        f32x4 acc = z;
        #pragma unroll
        for (int kd = 0; kd < 4; kd++) {
          s16x8 bf = *(const s16x8*)(w1_bf + (size_t)(n * 16 + lr) * E + kd * 32 + lg * 8);
          acc = __builtin_amdgcn_mfma_f32_16x16x32_bf16(gf[kd], bf, acc, 0, 0, 0);
        }
        float b1v = b1g[n * 16 + lr];
        #pragma unroll
        for (int v = 0; v < 4; v++)
          h_l[hidx(w * 16 + lg * 4 + v, n * 16 + lr)] = f2b(fmaxf(acc[v] + b1v, 0.f));
      }
    }
    __syncthreads();
    // ---- phase C: out = h @ w2^T ; update att ; hist ----
    {
      s16x8 hf[8];
      #pragma unroll
      for (int kk = 0; kk < 8; kk++)
        hf[kk] = *(const s16x8*)&h_l[hidx(w * 16 + lr, kk * 32 + lg * 8)];
      int op = prog_op[b * T + t];
      float insF = (op == 1) ? 1.f : 0.f, trF = (op == 2) ? 1.f : 0.f;
      float projv[4];
      #pragma unroll
      for (int v = 0; v < 4; v++)
        projv[v] = proj_all[(size_t)(t * B + b) * C + j0 + w * 16 + lg * 4 + v];
      #pragma unroll
      for (int n = 0; n < 4; n++) {
        f32x4 acc = z;
        #pragma unroll
        for (int kk = 0; kk < 8; kk++) {
          s16x8 bf = *(const s16x8*)(w2_bf + (size_t)(n * 16 + lr) * HD + kk * 32 + lg * 8);
          acc = __builtin_amdgcn_mfma_f32_16x16x32_bf16(hf[kk], bf, acc, 0, 0, 0);
        }
        int a = n * 16 + lr;
        float b2v = b2g[a];
        float meta_a = meta_all[(size_t)(t * B + b) * AD + a];
        #pragma unroll
        for (int v = 0; v < 4; v++) {
          int row = lg * 4 + v;
          int i = j0 + w * 16 + row;
          float transfer = acc[v] + b2v + b2f(g_l[gidx(w * 16 + row, 64 + a)]);
          float insert = meta_a * projv[v];
          float attv = att[n][v] + insF * insert + trF * transfer;
          attv = (attv >= 0.f) ? attv : 0.01f * attv;
          attv = fminf(fmaxf(attv, -1.f), 2.f);
          att[n][v] = attv;
          size_t hi = (((size_t)t * B + b) * C + i) * AD + a;
          __builtin_nontemporal_store(attv, att_hist + hi);
          __builtin_nontemporal_store(insert, ins_hist + hi);
          __builtin_nontemporal_store(transfer, trans_hist + hi);
        }
      }
    }
    // ---- epilogue: amean; publish next siaT + cflag (except last step) ----
    {
      float s[4];
      #pragma unroll
      for (int v = 0; v < 4; v++) s[v] = att[0][v] + att[1][v] + att[2][v] + att[3][v];
      #pragma unroll
      for (int v = 0; v < 4; v++) {
        s[v] += __shfl_xor(s[v], 1, 64);
        s[v] += __shfl_xor(s[v], 2, 64);
        s[v] += __shfl_xor(s[v], 4, 64);
        s[v] += __shfl_xor(s[v], 8, 64);
        amr[v] = s[v] * (1.f / AD);
      }
      if (lr == 0) {
        #pragma unroll
        for (int v = 0; v < 4; v++) am_l[w * 16 + lg * 4 + v] = amr[v];
      }
    }
    if (t < T - 1) {
      // att-half of next siaT (coherent)
      #pragma unroll
      for (int n = 0; n < 4; n++) {
        unsigned long long pk = 0;
        #pragma unroll
        for (int v = 0; v < 4; v++)
          pk |= (unsigned long long)f2b(att[n][v] * amr[v]) << (16 * v);
        st_coh_u64((unsigned long long*)(siaT + (size_t)(b * 128 + 64 + n * 16 + lr) * C + j0 + w * 16 + lg * 4), pk);
      }
      __syncthreads();   // am_l ready for id-half
      #pragma unroll
      for (int k2 = 0; k2 < 2; k2++) {
        int idx = tid + k2 * 256;
        int d = idx >> 3, part = idx & 7;
        int j = part * 8;
        s16x8 iv = *(const s16x8*)(idT_g + (size_t)(b * 64 + d) * C + j0 + j);
        union { s16x8 v; unsigned long long u[2]; } ov;
        #pragma unroll
        for (int m = 0; m < 8; m++)
          ov.v[m] = (short)f2b(b2f((unsigned short)iv[m]) * am_l[j + m]);
        unsigned long long* dst = (unsigned long long*)(siaT + (size_t)(b * 128 + d) * C + j0 + j);
        st_coh_u64(dst, ov.u[0]);
        st_coh_u64(dst + 1, ov.u[1]);
      }
      asm volatile("s_waitcnt vmcnt(0)" ::: "memory");
      __syncthreads();
      if (tid == 0) st_coh_u32(cflag + b * 34 + ch, ph);
      __syncthreads();
    }
  }
  // ---- tail: rowmean + per-batch log-softmax (ch==0 block) ----
  if (lr == 0) {
    #pragma unroll
    for (int v = 0; v < 4; v++)
      st_coh_f32(rowmean + (size_t)b * C + j0 + w * 16 + lg * 4 + v, amr[v]);
  }
  asm volatile("s_waitcnt vmcnt(0)" ::: "memory");
  __syncthreads();
  if (tid == 0) st_coh_u32(sflag + b * 34 + ch, 1u);
  if (ch == 0) {
    if (tid < 34) {
      while (ld_coh_u32(sflag + b * 34 + tid) < 1u) __builtin_amdgcn_s_sleep(2);
    }
    __syncthreads();
    float* am = (float*)smem;
    for (int i = tid; i < C; i += 256) am[i] = ld_coh_f32(rowmean + (size_t)b * C + i);
    __syncthreads();
    float mx = -1e30f;
    for (int i = tid; i < C; i += 256) mx = fmaxf(mx, am[i]);
    red[tid] = mx; __syncthreads();
    for (int s2 = 128; s2 > 0; s2 >>= 1) { if (tid < s2) red[tid] = fmaxf(red[tid], red[tid + s2]); __syncthreads(); }
    mx = red[0]; __syncthreads();
    float sm = 0.f;
    for (int i = tid; i < C; i += 256) sm += expf(am[i] - mx);
    red[tid] = sm; __syncthreads();
    for (int s2 = 128; s2 > 0; s2 >>= 1) { if (tid < s2) red[tid] += red[tid + s2]; __syncthreads(); }
    float lse = logf(red[0]) + mx;
    for (int i = tid; i < C; i += 256) out[(size_t)b * C + i] = am[i] - lse;
  }
}

extern "C" void kernel_launch(void* const* d_in, const int* in_sizes, int n_in,
                              void* d_out, int out_size, void* d_ws, size_t ws_size,
                              hipStream_t stream) {
  const int* scene     = (const int*)d_in[0];
  const int* prog_op   = (const int*)d_in[1];
  const int* prog_arg  = (const int*)d_in[2];
  const float* aein    = (const float*)d_in[3];
  const float* aeout   = (const float*)d_in[4];
  const float* aeid    = (const float*)d_in[5];
  const float* cein    = (const float*)d_in[6];
  const float* ceout   = (const float*)d_in[7];
  const float* ceid    = (const float*)d_in[8];
  const float* att_init = (const float*)d_in[11];
  const float* aw1 = (const float*)d_in[12];
  const float* ab1 = (const float*)d_in[13];
  const float* aw2 = (const float*)d_in[14];
  const float* ab2 = (const float*)d_in[15];
  const float* mw1 = (const float*)d_in[16];
  const float* mb1 = (const float*)d_in[17];
  const float* mw2 = (const float*)d_in[18];
  const float* mb2 = (const float*)d_in[19];

  char* ws = (char*)d_ws;
  size_t off = 0;
  auto carve = [&](size_t bytes) { char* p = ws + off; off += (bytes + 255) & ~(size_t)255; return p; };
  float* axon      = (float*)carve((size_t)B * C * E * 4);
  float* identity  = (float*)carve((size_t)B * C * IDD * 4);
  float* proj_all  = (float*)carve((size_t)T * B * C * 4);
  float* meta_all  = (float*)carve((size_t)T * B * AD * 4);
  float* mw1T      = (float*)carve((size_t)192 * HD * 4);
  float* mw2T      = (float*)carve((size_t)HD * AD * 4);
  float* rowmean   = (float*)carve((size_t)B * C * 4);
  unsigned short* dendron_bf = (unsigned short*)carve((size_t)B * C * E * 2);
  unsigned short* axonT      = (unsigned short*)carve((size_t)B * E * C * 2);
  unsigned short* idT_g      = (unsigned short*)carve((size_t)B * 64 * C * 2);
  unsigned short* siaT       = (unsigned short*)carve((size_t)B * 128 * C * 2);
  unsigned long long* Mt64   = (unsigned long long*)carve((size_t)B * 4096 * 8);
  unsigned short* w1_bf      = (unsigned short*)carve((size_t)HD * E * 2);
  unsigned short* w2_bf      = (unsigned short*)carve((size_t)AD * HD * 2);
  unsigned*       flags      = (unsigned*)carve(4096);
  unsigned*       mflag = flags;            // [8][4]
  unsigned*       cflag = flags + 32;       // [8][34]
  unsigned*       sflag = flags + 304;      // [8][34]

  float* out_sm     = (float*)d_out;
  float* att_hist   = out_sm + B * C;
  float* ins_hist   = att_hist + (size_t)T * B * C * AD;
  float* trans_hist = ins_hist + (size_t)T * B * C * AD;

  k_setup1<<<dim3(4545), dim3(256), 0, stream>>>(scene, aein, aeout, aeid, cein, ceout, ceid,
                                                 aw1, aw2, mw1, mw2,
                                                 dendron_bf, axon, identity,
                                                 w1_bf, w2_bf, mw1T, mw2T, flags);
  k_setup2<<<dim3(1368), dim3(256), 0, stream>>>(axon, identity, att_init,
                                                 prog_op, prog_arg, ceout,
                                                 mw1T, mb1, mw2T, mb2,
                                                 axonT, idT_g, siaT,
                                                 meta_all, proj_all);
  k_steps<<<dim3(272), dim3(256), 0, stream>>>(dendron_bf, axonT, idT_g, siaT,
                                               w1_bf, ab1, w2_bf, ab2,
                                               proj_all, meta_all, prog_op, att_init,
                                               Mt64, rowmean, out_sm,
                                               att_hist, ins_hist, trans_hist,
                                               mflag, cflag, sflag);
}

// Round 9
// 828.132 us; speedup vs baseline: 1.9073x; 1.9073x over previous
//
#include <hip/hip_runtime.h>

#define B 8
#define NOBJ 128
#define NATTR 4
#define T 12
#define MC 2048
#define E 128
#define IDD 64
#define AD 64
#define HD 256
#define C 2176

typedef short s16x8 __attribute__((ext_vector_type(8)));
typedef float f32x4 __attribute__((ext_vector_type(4)));

__device__ inline unsigned short f2b(float f) {
  union { float f; unsigned u; } v; v.f = f;
  unsigned r = v.u + 0x7FFFu + ((v.u >> 16) & 1u);
  return (unsigned short)(r >> 16);
}
__device__ inline float b2f(unsigned short u) {
  union { unsigned u; float f; } v; v.u = ((unsigned)u) << 16;
  return v.f;
}

// LDS swizzles: XOR row bits into the 16B-slot index (conflict-free b128 access)
__device__ __forceinline__ int gidx(int r, int c) {   // g [64][128]
  return r * 128 + ((((c >> 3) ^ (r & 15)) << 3) | (c & 7));
}
__device__ __forceinline__ int hidx(int r, int c) {   // h [64][256]
  return r * 256 + ((((c >> 3) ^ (r & 15)) << 3) | (c & 7));
}
__device__ __forceinline__ int mtidx(int r, int c) {  // mt/stg [128][128]
  return r * 128 + ((((c >> 3) ^ (r & 15)) << 3) | (c & 7));
}

// ---------------- setup kernel 1: build + weight cvt ----------------
__global__ __launch_bounds__(256) void k_setup1(
    const int* __restrict__ scene,
    const float* __restrict__ aein, const float* __restrict__ aeout,
    const float* __restrict__ aeid,
    const float* __restrict__ cein, const float* __restrict__ ceout,
    const float* __restrict__ ceid,
    const float* __restrict__ aw1, const float* __restrict__ aw2,
    const float* __restrict__ mw1, const float* __restrict__ mw2,
    unsigned short* __restrict__ dendron_bf, float* __restrict__ axon,
    float* __restrict__ identity,
    unsigned short* __restrict__ w1_bf, unsigned short* __restrict__ w2_bf,
    float* __restrict__ mw1T, float* __restrict__ mw2T) {
  int blk = blockIdx.x;
  int tid = threadIdx.x;
  if (blk < 4352) {
    int gid = blk * 2 + (tid >> 7);
    int e = tid & 127;
    int b = gid / C, j = gid % C;
    float din, dout, did = 0.f;
    if (j < MC) {
      din  = cein[j * E + e];
      dout = ceout[j * E + e];
      if (e < IDD) did = ceid[j * IDD + e];
    } else {
      int obj = j - MC;
      float sIn = 0.f, sOut = 0.f, sId = 0.f;
      for (int a = 0; a < NATTR; a++) {
        int s = scene[(b * NOBJ + obj) * NATTR + a];
        float m = (s != -1) ? 1.f : 0.f;
        int idx = s + 1;
        sIn  += aein[idx * E + e] * m;
        sOut += aeout[idx * E + e] * m;
        if (e < IDD) sId += aeid[idx * IDD + e] * m;
      }
      din = sIn; dout = sOut; did = sId;
    }
    dendron_bf[(size_t)gid * E + e] = f2b(din);
    axon[(size_t)gid * E + e] = dout;
    if (e < IDD) identity[(size_t)gid * IDD + e] = did;
  } else {
    int i = (blk - 4352) * 256 + tid;
    if (i < HD * E)  w1_bf[i] = f2b(aw1[i]);
    if (i < AD * HD) w2_bf[i] = f2b(aw2[i]);
    if (i < 192 * HD) { int c = i / HD, k = i % HD; mw1T[c * HD + k] = mw1[k * 192 + c]; }
    if (i < HD * AD)  { int k = i / AD, a = i % AD; mw2T[k * AD + a] = mw2[a * HD + k]; }
  }
}

// ---------------- setup kernel 2: transA/init + meta + proj ----------------
__global__ __launch_bounds__(256) void k_setup2(
    const float* __restrict__ axon, const float* __restrict__ identity,
    const float* __restrict__ att_init,
    const int* __restrict__ prog_op, const int* __restrict__ prog_arg,
    const float* __restrict__ ceout,
    const float* __restrict__ mw1T, const float* __restrict__ mb1,
    const float* __restrict__ mw2T, const float* __restrict__ mb2,
    unsigned short* __restrict__ axonT, unsigned short* __restrict__ idT_g,
    unsigned short* __restrict__ siaT, float* __restrict__ att_g,
    float* __restrict__ meta_all, float* __restrict__ proj_all) {
  int blk = blockIdx.x;
  int tid = threadIdx.x;
  if (blk < 272) {
    int b = blk / 34, jc = blk % 34;
    int j0 = jc * 64;
    __shared__ float ax[64][129];
    __shared__ float idb[64][65];
    int lane = tid & 63, lr = lane & 15;
    float s = att_init[lane];
    s += __shfl_xor(s, 1, 64);  s += __shfl_xor(s, 2, 64);
    s += __shfl_xor(s, 4, 64);  s += __shfl_xor(s, 8, 64);
    s += __shfl_xor(s, 16, 64); s += __shfl_xor(s, 32, 64);
    float am0 = s * (1.f / AD);
    for (int i = tid; i < 64 * 128; i += 256) {
      int j = i >> 7, e = i & 127;
      ax[j][e] = axon[(size_t)(b * C + j0 + j) * E + e];
    }
    for (int i = tid; i < 64 * 64; i += 256) {
      int j = i >> 6, d = i & 63;
      idb[j][d] = identity[(size_t)(b * C + j0 + j) * IDD + d];
    }
    __syncthreads();
    for (int i = tid; i < 128 * 64; i += 256) {
      int e = i >> 6, jj = i & 63;
      axonT[(size_t)(b * E + e) * C + j0 + jj] = f2b(ax[jj][e]);
    }
    for (int i = tid; i < 64 * 64; i += 256) {
      int d = i >> 6, jj = i & 63;
      idT_g[(size_t)(b * 64 + d) * C + j0 + jj] = f2b(idb[jj][d]);
      siaT[(size_t)(b * 128 + d) * C + j0 + jj] = f2b(idb[jj][d] * am0);
      siaT[(size_t)(b * 128 + 64 + d) * C + j0 + jj] = f2b(att_init[d] * am0);
    }
    {
      float* ag = att_g + (size_t)blk * 4096 + tid * 16;
      #pragma unroll
      for (int n = 0; n < 4; n++) {
        float v0 = att_init[n * 16 + lr];
        #pragma unroll
        for (int v = 0; v < 4; v++) ag[n * 4 + v] = v0;
      }
    }
  } else if (blk < 280) {
    int b = blk - 272;
    __shared__ float x[192];
    __shared__ float h[HD];
    __shared__ float meta[AD];
    if (tid < AD) meta[tid] = att_init[tid];
    __syncthreads();
    for (int t = 0; t < T; t++) {
      int arg = prog_arg[b * T + t];
      if (tid < AD) x[tid] = meta[tid];
      else if (tid < 192) x[tid] = ceout[arg * E + (tid - 64)];
      __syncthreads();
      float s = mb1[tid];
      for (int c = 0; c < 192; c++) s += x[c] * mw1T[c * HD + tid];
      h[tid] = fmaxf(s, 0.f);
      __syncthreads();
      if (tid < AD) {
        float o = mb2[tid];
        for (int k = 0; k < HD; k++) o += h[k] * mw2T[k * AD + tid];
        float m = (prog_op[b * T + t] == 0) ? 1.f : 0.f;
        float nm = m * o + (1.f - m) * meta[tid];
        meta[tid] = nm;
        meta_all[(t * B + b) * AD + tid] = nm;
      }
      __syncthreads();
    }
  } else {
    int gid = (blk - 280) * 4 + (tid >> 6);
    int lane = tid & 63;
    int b = gid / C, i = gid % C;
    float a0 = axon[(size_t)gid * E + lane];
    float a1 = axon[(size_t)gid * E + 64 + lane];
    for (int t = 0; t < T; t++) {
      int arg = prog_arg[b * T + t];
      float p = a0 * ceout[arg * E + lane] + a1 * ceout[arg * E + 64 + lane];
      for (int off = 1; off < 64; off <<= 1) p += __shfl_xor(p, off, 64);
      if (lane == 0) proj_all[(size_t)(t * B + b) * C + i] = p * (1.f / E);
    }
  }
}

// ---------------- per-step kernel: redundant M GEMM + phases + epilogue ----
// No atomics/flags. Cross-step state passes through the kernel boundary.
__global__ __launch_bounds__(256, 2) void k_step(
    int t,
    const unsigned short* __restrict__ dendron_bf,
    const unsigned short* __restrict__ axonT,
    const unsigned short* __restrict__ idT_g,
    const unsigned short* __restrict__ siaA,   // input sia (read-only this launch)
    unsigned short* __restrict__ siaB,         // output sia for next step
    const unsigned short* __restrict__ w1_bf, const float* __restrict__ b1g,
    const unsigned short* __restrict__ w2_bf, const float* __restrict__ b2g,
    const float* __restrict__ proj_all, const float* __restrict__ meta_all,
    const int* __restrict__ prog_op,
    float* __restrict__ att_g, float* __restrict__ rowmean,
    float* __restrict__ att_hist, float* __restrict__ ins_hist,
    float* __restrict__ trans_hist) {
  const int blk = blockIdx.x;
  const int b = blk / 34, ch = blk % 34, j0 = ch * 64;
  const int tid = threadIdx.x;
  const int w = tid >> 6, lane = tid & 63, lr = lane & 15, lg = lane >> 4;

  __shared__ unsigned short smem[32768];        // 64 KB overlay
  __shared__ float am_l[64];
  unsigned short* stgA = smem;                  // GEMM staging  [0,16384) elems
  unsigned short* stgB = smem + 16384;          //               [16384,32768)
  unsigned short* mt   = smem;                  // M result (after GEMM)
  unsigned short* h_l  = smem;                  // h overlays mt in phase B
  unsigned short* g_l  = smem + 16384;          // g overlays stgB in phase A

  const f32x4 z = {0.f, 0.f, 0.f, 0.f};

  // attention state (blocked, coalesced)
  float att[4][4];
  {
    const f32x4* ag = (const f32x4*)(att_g + (size_t)blk * 4096 + tid * 16);
    #pragma unroll
    for (int n = 0; n < 4; n++) {
      f32x4 v4 = ag[n];
      #pragma unroll
      for (int v = 0; v < 4; v++) att[n][v] = v4[v];
    }
  }

  // ---- redundant GEMM: M[128][128] = siaA[b] @ axonT[b]^T over K=C ----
  // wave tile 64x64: d-half = (w>>1)*64, e-half = (w&1)*64
  f32x4 acc[4][4];
  #pragma unroll
  for (int dt = 0; dt < 4; dt++)
    #pragma unroll
    for (int n = 0; n < 4; n++) acc[dt][n] = z;
  const int d0 = (w >> 1) * 64, e0 = (w & 1) * 64;
  const unsigned short* gAb = siaA + (size_t)b * 128 * C;
  const unsigned short* gBb = axonT + (size_t)b * E * C;
  for (int kc = 0; kc < 17; kc++) {
    __syncthreads();
    const unsigned short* gA = gAb + kc * 128;
    const unsigned short* gB = gBb + kc * 128;
    #pragma unroll
    for (int q = 0; q < 8; q++) {
      int idx = tid + q * 256;                  // 2048 16B slots
      int row = idx >> 4, slot = idx & 15;
      int ds = row * 128 + ((slot ^ (row & 15)) << 3);
      *(s16x8*)&stgA[ds] = *(const s16x8*)(gA + (size_t)row * C + slot * 8);
      *(s16x8*)&stgB[ds] = *(const s16x8*)(gB + (size_t)row * C + slot * 8);
    }
    __syncthreads();
    #pragma unroll
    for (int ks = 0; ks < 4; ks++) {
      s16x8 af[4], bfr[4];
      #pragma unroll
      for (int dt = 0; dt < 4; dt++) {
        int r = d0 + dt * 16 + lr;
        af[dt] = *(const s16x8*)&stgA[r * 128 + (((ks * 4 + lg) ^ (r & 15)) << 3)];
      }
      #pragma unroll
      for (int n = 0; n < 4; n++) {
        int r = e0 + n * 16 + lr;
        bfr[n] = *(const s16x8*)&stgB[r * 128 + (((ks * 4 + lg) ^ (r & 15)) << 3)];
      }
      #pragma unroll
      for (int n = 0; n < 4; n++)
        #pragma unroll
        for (int dt = 0; dt < 4; dt++)
          acc[dt][n] = __builtin_amdgcn_mfma_f32_16x16x32_bf16(af[dt], bfr[n], acc[dt][n], 0, 0, 0);
    }
  }
  __syncthreads();
  // acc -> mt (bf16, swizzled). M[d][e]; C/D layout: d = d0+dt*16+lg*4+v, e = e0+n*16+lr
  #pragma unroll
  for (int dt = 0; dt < 4; dt++)
    #pragma unroll
    for (int n = 0; n < 4; n++)
      #pragma unroll
      for (int v = 0; v < 4; v++)
        mt[mtidx(d0 + dt * 16 + lg * 4 + v, e0 + n * 16 + lr)] = f2b(acc[dt][n][v]);
  __syncthreads();
  // ---- phase A: g = dendron @ M / C ----
  {
    s16x8 afr[4];
    #pragma unroll
    for (int ke = 0; ke < 4; ke++)
      afr[ke] = *(const s16x8*)(dendron_bf + (size_t)(b * C + j0 + w * 16 + lr) * E + ke * 32 + lg * 8);
    #pragma unroll
    for (int n = 0; n < 8; n++) {
      f32x4 a2 = z;
      #pragma unroll
      for (int ke = 0; ke < 4; ke++) {
        s16x8 bf = *(const s16x8*)&mt[mtidx(n * 16 + lr, ke * 32 + lg * 8)];
        a2 = __builtin_amdgcn_mfma_f32_16x16x32_bf16(afr[ke], bf, a2, 0, 0, 0);
      }
      #pragma unroll
      for (int v = 0; v < 4; v++)
        g_l[gidx(w * 16 + lg * 4 + v, n * 16 + lr)] = f2b(a2[v] * (1.f / C));
    }
  }
  __syncthreads();
  // ---- phase B: h = relu(g @ w1^T + b1)  (h overwrites mt region) ----
  {
    s16x8 gf[4];
    #pragma unroll
    for (int kd = 0; kd < 4; kd++)
      gf[kd] = *(const s16x8*)&g_l[gidx(w * 16 + lr, kd * 32 + lg * 8)];
    #pragma unroll
    for (int n = 0; n < 16; n++) {
      f32x4 a2 = z;
      #pragma unroll
      for (int kd = 0; kd < 4; kd++) {
        s16x8 bf = *(const s16x8*)(w1_bf + (size_t)(n * 16 + lr) * E + kd * 32 + lg * 8);
        a2 = __builtin_amdgcn_mfma_f32_16x16x32_bf16(gf[kd], bf, a2, 0, 0, 0);
      }
      float b1v = b1g[n * 16 + lr];
      #pragma unroll
      for (int v = 0; v < 4; v++)
        h_l[hidx(w * 16 + lg * 4 + v, n * 16 + lr)] = f2b(fmaxf(a2[v] + b1v, 0.f));
    }
  }
  __syncthreads();
  // ---- phase C: out = h @ w2^T ; update att ; hist ----
  {
    s16x8 hf[8];
    #pragma unroll
    for (int kk = 0; kk < 8; kk++)
      hf[kk] = *(const s16x8*)&h_l[hidx(w * 16 + lr, kk * 32 + lg * 8)];
    int op = prog_op[b * T + t];
    float insF = (op == 1) ? 1.f : 0.f, trF = (op == 2) ? 1.f : 0.f;
    float projv[4];
    #pragma unroll
    for (int v = 0; v < 4; v++)
      projv[v] = proj_all[(size_t)(t * B + b) * C + j0 + w * 16 + lg * 4 + v];
    #pragma unroll
    for (int n = 0; n < 4; n++) {
      f32x4 a2 = z;
      #pragma unroll
      for (int kk = 0; kk < 8; kk++) {
        s16x8 bf = *(const s16x8*)(w2_bf + (size_t)(n * 16 + lr) * HD + kk * 32 + lg * 8);
        a2 = __builtin_amdgcn_mfma_f32_16x16x32_bf16(hf[kk], bf, a2, 0, 0, 0);
      }
      int a = n * 16 + lr;
      float b2v = b2g[a];
      float meta_a = meta_all[(size_t)(t * B + b) * AD + a];
      #pragma unroll
      for (int v = 0; v < 4; v++) {
        int row = lg * 4 + v;
        int i = j0 + w * 16 + row;
        float transfer = a2[v] + b2v + b2f(g_l[gidx(w * 16 + row, 64 + a)]);
        float insert = meta_a * projv[v];
        float attv = att[n][v] + insF * insert + trF * transfer;
        attv = (attv >= 0.f) ? attv : 0.01f * attv;
        attv = fminf(fmaxf(attv, -1.f), 2.f);
        att[n][v] = attv;
        size_t hi = (((size_t)t * B + b) * C + i) * AD + a;
        __builtin_nontemporal_store(attv, att_hist + hi);
        __builtin_nontemporal_store(insert, ins_hist + hi);
        __builtin_nontemporal_store(transfer, trans_hist + hi);
      }
    }
  }
  // ---- epilogue: amean; store att_g, next siaT, rowmean ----
  float amr[4];
  {
    float s[4];
    #pragma unroll
    for (int v = 0; v < 4; v++) s[v] = att[0][v] + att[1][v] + att[2][v] + att[3][v];
    #pragma unroll
    for (int v = 0; v < 4; v++) {
      s[v] += __shfl_xor(s[v], 1, 64);
      s[v] += __shfl_xor(s[v], 2, 64);
      s[v] += __shfl_xor(s[v], 4, 64);
      s[v] += __shfl_xor(s[v], 8, 64);
      amr[v] = s[v] * (1.f / AD);
    }
    if (lr == 0) {
      #pragma unroll
      for (int v = 0; v < 4; v++) am_l[w * 16 + lg * 4 + v] = amr[v];
    }
  }
  {
    f32x4* ag = (f32x4*)(att_g + (size_t)blk * 4096 + tid * 16);
    #pragma unroll
    for (int n = 0; n < 4; n++) {
      f32x4 v4;
      #pragma unroll
      for (int v = 0; v < 4; v++) v4[v] = att[n][v];
      ag[n] = v4;
      unsigned long long pk = 0;
      #pragma unroll
      for (int v = 0; v < 4; v++)
        pk |= (unsigned long long)f2b(att[n][v] * amr[v]) << (16 * v);
      *(unsigned long long*)(siaB + (size_t)(b * 128 + 64 + n * 16 + lr) * C + j0 + w * 16 + lg * 4) = pk;
    }
  }
  if (t == T - 1 && lr == 0) {
    #pragma unroll
    for (int v = 0; v < 4; v++)
      rowmean[(size_t)b * C + j0 + w * 16 + lg * 4 + v] = amr[v];
  }
  __syncthreads();   // am_l ready
  // id half of next siaT
  #pragma unroll
  for (int k2 = 0; k2 < 2; k2++) {
    int idx = tid + k2 * 256;
    int d = idx >> 3, part = idx & 7;
    int j = part * 8;
    s16x8 iv = *(const s16x8*)(idT_g + (size_t)(b * 64 + d) * C + j0 + j);
    s16x8 ov;
    #pragma unroll
    for (int m = 0; m < 8; m++)
      ov[m] = (short)f2b(b2f((unsigned short)iv[m]) * am_l[j + m]);
    *(s16x8*)(siaB + (size_t)(b * 128 + d) * C + j0 + j) = ov;
  }
}

// ---------------- final softmax ----------------
__global__ void k_softmax(const float* __restrict__ rowmean, float* __restrict__ out) {
  int b = blockIdx.x;
  __shared__ float am[C];
  __shared__ float red[256];
  int tid = threadIdx.x;
  for (int i = tid; i < C; i += 256) am[i] = rowmean[(size_t)b * C + i];
  __syncthreads();
  float mx = -1e30f;
  for (int i = tid; i < C; i += 256) mx = fmaxf(mx, am[i]);
  red[tid] = mx; __syncthreads();
  for (int s = 128; s > 0; s >>= 1) { if (tid < s) red[tid] = fmaxf(red[tid], red[tid + s]); __syncthreads(); }
  mx = red[0]; __syncthreads();
  float sm = 0.f;
  for (int i = tid; i < C; i += 256) sm += expf(am[i] - mx);
  red[tid] = sm; __syncthreads();
  for (int s = 128; s > 0; s >>= 1) { if (tid < s) red[tid] += red[tid + s]; __syncthreads(); }
  float lse = logf(red[0]) + mx;
  for (int i = tid; i < C; i += 256) out[(size_t)b * C + i] = am[i] - lse;
}

extern "C" void kernel_launch(void* const* d_in, const int* in_sizes, int n_in,
                              void* d_out, int out_size, void* d_ws, size_t ws_size,
                              hipStream_t stream) {
  const int* scene     = (const int*)d_in[0];
  const int* prog_op   = (const int*)d_in[1];
  const int* prog_arg  = (const int*)d_in[2];
  const float* aein    = (const float*)d_in[3];
  const float* aeout   = (const float*)d_in[4];
  const float* aeid    = (const float*)d_in[5];
  const float* cein    = (const float*)d_in[6];
  const float* ceout   = (const float*)d_in[7];
  const float* ceid    = (const float*)d_in[8];
  const float* att_init = (const float*)d_in[11];
  const float* aw1 = (const float*)d_in[12];
  const float* ab1 = (const float*)d_in[13];
  const float* aw2 = (const float*)d_in[14];
  const float* ab2 = (const float*)d_in[15];
  const float* mw1 = (const float*)d_in[16];
  const float* mb1 = (const float*)d_in[17];
  const float* mw2 = (const float*)d_in[18];
  const float* mb2 = (const float*)d_in[19];

  char* ws = (char*)d_ws;
  size_t off = 0;
  auto carve = [&](size_t bytes) { char* p = ws + off; off += (bytes + 255) & ~(size_t)255; return p; };
  float* axon      = (float*)carve((size_t)B * C * E * 4);
  float* identity  = (float*)carve((size_t)B * C * IDD * 4);
  float* proj_all  = (float*)carve((size_t)T * B * C * 4);
  float* meta_all  = (float*)carve((size_t)T * B * AD * 4);
  float* mw1T      = (float*)carve((size_t)192 * HD * 4);
  float* mw2T      = (float*)carve((size_t)HD * AD * 4);
  float* rowmean   = (float*)carve((size_t)B * C * 4);
  float* att_g     = (float*)carve((size_t)272 * 4096 * 4);
  unsigned short* dendron_bf = (unsigned short*)carve((size_t)B * C * E * 2);
  unsigned short* axonT      = (unsigned short*)carve((size_t)B * E * C * 2);
  unsigned short* idT_g      = (unsigned short*)carve((size_t)B * 64 * C * 2);
  unsigned short* siaT0      = (unsigned short*)carve((size_t)B * 128 * C * 2);
  unsigned short* siaT1      = (unsigned short*)carve((size_t)B * 128 * C * 2);
  unsigned short* w1_bf      = (unsigned short*)carve((size_t)HD * E * 2);
  unsigned short* w2_bf      = (unsigned short*)carve((size_t)AD * HD * 2);

  float* out_sm     = (float*)d_out;
  float* att_hist   = out_sm + B * C;
  float* ins_hist   = att_hist + (size_t)T * B * C * AD;
  float* trans_hist = ins_hist + (size_t)T * B * C * AD;

  k_setup1<<<dim3(4544), dim3(256), 0, stream>>>(scene, aein, aeout, aeid, cein, ceout, ceid,
                                                 aw1, aw2, mw1, mw2,
                                                 dendron_bf, axon, identity,
                                                 w1_bf, w2_bf, mw1T, mw2T);
  k_setup2<<<dim3(1368), dim3(256), 0, stream>>>(axon, identity, att_init,
                                                 prog_op, prog_arg, ceout,
                                                 mw1T, mb1, mw2T, mb2,
                                                 axonT, idT_g, siaT0, att_g,
                                                 meta_all, proj_all);
  for (int t = 0; t < T; t++) {
    unsigned short* sin  = (t & 1) ? siaT1 : siaT0;
    unsigned short* sout = (t & 1) ? siaT0 : siaT1;
    k_step<<<dim3(272), dim3(256), 0, stream>>>(t, dendron_bf, axonT, idT_g, sin, sout,
                                                w1_bf, ab1, w2_bf, ab2,
                                                proj_all, meta_all, prog_op,
                                                att_g, rowmean,
                                                att_hist, ins_hist, trans_hist);
  }
  k_softmax<<<dim3(B), dim3(256), 0, stream>>>(rowmean, out_sm);
}